// Round 6
// baseline (461.399 us; speedup 1.0000x reference)
//
#include <hip/hip_runtime.h>
#include <math.h>

#define B_   32
#define T_   64
#define D_   300
#define H_   256
#define G4H  1024   // 4*H
#define M_   64
#define C_   5

typedef _Float16 h2v __attribute__((ext_vector_type(2)));
typedef _Float16 h8  __attribute__((ext_vector_type(8)));
typedef float    f4  __attribute__((ext_vector_type(4)));

__device__ __forceinline__ float sigmoidf_(float x) { return 1.0f / (1.0f + expf(-x)); }

__device__ __forceinline__ float dot2_(h2v a, h2v b, float c) {
#if __has_builtin(__builtin_amdgcn_fdot2)
    return __builtin_amdgcn_fdot2(a, b, c, false);
#else
    return c + (float)a[0] * (float)b[0] + (float)a[1] * (float)b[1];
#endif
}
__device__ __forceinline__ h2v pk_(float a, float b) {
    h2v t; t[0] = (_Float16)a; t[1] = (_Float16)b; return t;
}
__device__ __forceinline__ h2v bcu_(unsigned u) { return __builtin_bit_cast(h2v, u); }

// ---------------------------------------------------------------------------
// K1: length[b]
// ---------------------------------------------------------------------------
__global__ void k_length(const float* __restrict__ x, int* __restrict__ length) {
    const int b = blockIdx.x;
    const int t = threadIdx.x;  // 64 threads
    float mv = 0.f;
    const float* row = x + (size_t)(b * T_ + t) * D_;
    for (int d = 0; d < D_; ++d) mv = fmaxf(mv, fabsf(row[d]));
    unsigned long long m = __ballot(mv > 0.f);
    if (t == 0) length[b] = __popcll(m);
}

// ---------------------------------------------------------------------------
// K2: xw = x-part of gate pre-activations (+ bias). f16 MFMA GEMM.
// ---------------------------------------------------------------------------
__global__ void __launch_bounds__(256)
k_xw(const float* __restrict__ x,
     const float* __restrict__ Wfw, const float* __restrict__ bfw,
     const float* __restrict__ Wbw, const float* __restrict__ bbw,
     float* __restrict__ xw) {
    const int nt  = blockIdx.x;       // 0..15 col tile
    const int mt  = blockIdx.y;       // 0..15 row tile
    const int tid = threadIdx.x;      // 256
    const int w   = tid >> 6;         // wave 0..3
    const int l   = tid & 63;
    const int n0  = nt * 128, m0 = mt * 128;
    const int dir = n0 >> 10;               // 1024%128==0: tiles don't straddle
    const float* W    = dir ? Wbw : Wfw;
    const float* bias = dir ? bbw : bfw;
    const int ncol0 = n0 & 1023;

    __shared__ __align__(16) _Float16 As[128][40];  // 32 k + 8 pad
    __shared__ __align__(16) _Float16 Bs[128][40];  // [col][k]

    f4 acc[4][4];
    #pragma unroll
    for (int i = 0; i < 4; ++i)
        #pragma unroll
        for (int j = 0; j < 4; ++j) acc[i][j] = (f4){0.f, 0.f, 0.f, 0.f};

    const int wr = (w >> 1) * 64;   // wave row quadrant
    const int wc = (w & 1) * 64;    // wave col quadrant

    for (int k0 = 0; k0 < 320; k0 += 32) {
        #pragma unroll
        for (int r = 0; r < 16; ++r) {
            int row = r * 8 + (tid >> 5);
            int kk  = tid & 31;
            int k   = k0 + kk;
            As[row][kk] = (k < D_) ? (_Float16)x[(size_t)(m0 + row) * D_ + k]
                                   : (_Float16)0.f;
        }
        #pragma unroll
        for (int r = 0; r < 16; ++r) {
            int col = (tid & 31) + (r & 3) * 32;
            int kk  = (tid >> 5) + (r >> 2) * 8;
            int k   = k0 + kk;
            Bs[col][kk] = (k < D_) ? (_Float16)W[(size_t)k * G4H + ncol0 + col]
                                   : (_Float16)0.f;
        }
        __syncthreads();

        h8 afr[4], bfr[4];
        #pragma unroll
        for (int fr = 0; fr < 4; ++fr)
            afr[fr] = *(const h8*)&As[wr + fr * 16 + (l & 15)][(l >> 4) * 8];
        #pragma unroll
        for (int fc = 0; fc < 4; ++fc)
            bfr[fc] = *(const h8*)&Bs[wc + fc * 16 + (l & 15)][(l >> 4) * 8];
        #pragma unroll
        for (int fr = 0; fr < 4; ++fr)
            #pragma unroll
            for (int fc = 0; fc < 4; ++fc)
                acc[fr][fc] = __builtin_amdgcn_mfma_f32_16x16x32_f16(
                    afr[fr], bfr[fc], acc[fr][fc], 0, 0, 0);
        __syncthreads();
    }

    #pragma unroll
    for (int fc = 0; fc < 4; ++fc) {
        int col = ncol0 + wc + fc * 16 + (l & 15);
        float bv = bias[col];
        #pragma unroll
        for (int fr = 0; fr < 4; ++fr) {
            #pragma unroll
            for (int e = 0; e < 4; ++e) {
                int row = m0 + wr + fr * 16 + (l >> 4) * 4 + e;
                xw[(size_t)dir * 2048 * G4H + (size_t)row * G4H + col] =
                    acc[fr][fc][e] + bv;
            }
        }
    }
}

// ---------------------------------------------------------------------------
// K3: LSTM recurrence — ONE block per (dir,b) chain, NO cross-block sync.
// 64 blocks x 512 threads. The full 512 KB f16 W_h for the chain is on-CU:
//   - k 0..191  (96 h2v per col): REGISTERS (192 VGPR/thread)
//   - k 192..255 (32 h2v per col): LDS wlds[64][512] (128 KB, [i][tid] layout
//     -> 2-way bank aliasing = free)
// Thread tid owns gate-cols c0=tid, c1=tid+512 (full K=256 each).
// Per step: 32 broadcast b128 reads of h + 256 fdot2, 2 barriers. Gates on
// tid<256 (h-col j=tid). h kept as f16 in a 512 B LDS buffer.
// ---------------------------------------------------------------------------
__global__ void __launch_bounds__(512, 2)
k_lstm(const float* __restrict__ Wfw, const float* __restrict__ Wbw,
       const float* __restrict__ xw, const int* __restrict__ length,
       float* __restrict__ lout) {
    const int dir = blockIdx.x >> 5;
    const int b   = blockIdx.x & 31;
    const int tid = threadIdx.x;     // 0..511
    const int c0  = tid;             // gate-col (gate = c>>8, jj = c&255)
    const int c1  = tid + 512;

    __shared__ unsigned wlds[64][512];          // 128 KB W tail (h2v words)
    __shared__ __align__(16) _Float16 hl[256];  // current h (f16)
    __shared__ float zfin[1024];

    const float* Wg = (dir ? Wbw : Wfw) + (size_t)D_ * G4H;  // rows 300..555

    // ---- stage W: k 0..191 into regs, k 192..255 into LDS ----
    h2v wA[96], wB[96];
    #pragma unroll
    for (int p = 0; p < 96; ++p) {
        wA[p] = pk_(Wg[(size_t)(2 * p) * G4H + c0], Wg[(size_t)(2 * p + 1) * G4H + c0]);
        wB[p] = pk_(Wg[(size_t)(2 * p) * G4H + c1], Wg[(size_t)(2 * p + 1) * G4H + c1]);
    }
    #pragma unroll
    for (int i = 0; i < 32; ++i) {
        int k = 192 + 2 * i;
        wlds[i][tid] = __builtin_bit_cast(unsigned,
            pk_(Wg[(size_t)k * G4H + c0], Wg[(size_t)(k + 1) * G4H + c0]));
        wlds[i + 32][tid] = __builtin_bit_cast(unsigned,
            pk_(Wg[(size_t)k * G4H + c1], Wg[(size_t)(k + 1) * G4H + c1]));
    }
    if (tid < 256) hl[tid] = (_Float16)0.f;
    const int len = length[b];
    const size_t xrow = (size_t)(dir * B_ + b) * T_;
    __syncthreads();

    float cst = 0.f, hprev = 0.f;
    const uint4* h4p = (const uint4*)hl;

    for (int s = 0; s < T_; ++s) {
        const int tt = dir ? (T_ - 1 - s) : s;

        // x-parts (L3-resident xw), issued early
        float xv0 = xw[(xrow + tt) * G4H + c0];
        float xv1 = xw[(xrow + tt) * G4H + c1];

        // ---- dot over K=256 for both owned columns ----
        float a0 = 0.f, a1 = 0.f;
        #pragma unroll
        for (int q = 0; q < 24; ++q) {          // k 0..191 from registers
            uint4 hv = h4p[q];
            h2v h0 = bcu_(hv.x), h1 = bcu_(hv.y), h2 = bcu_(hv.z), h3 = bcu_(hv.w);
            a0 = dot2_(wA[4 * q + 0], h0, a0);
            a0 = dot2_(wA[4 * q + 1], h1, a0);
            a0 = dot2_(wA[4 * q + 2], h2, a0);
            a0 = dot2_(wA[4 * q + 3], h3, a0);
            a1 = dot2_(wB[4 * q + 0], h0, a1);
            a1 = dot2_(wB[4 * q + 1], h1, a1);
            a1 = dot2_(wB[4 * q + 2], h2, a1);
            a1 = dot2_(wB[4 * q + 3], h3, a1);
        }
        #pragma unroll
        for (int q = 24; q < 32; ++q) {         // k 192..255 from LDS
            uint4 hv = h4p[q];
            h2v h0 = bcu_(hv.x), h1 = bcu_(hv.y), h2 = bcu_(hv.z), h3 = bcu_(hv.w);
            const int i = (q - 24) * 4;
            a0 = dot2_(bcu_(wlds[i + 0][tid]), h0, a0);
            a0 = dot2_(bcu_(wlds[i + 1][tid]), h1, a0);
            a0 = dot2_(bcu_(wlds[i + 2][tid]), h2, a0);
            a0 = dot2_(bcu_(wlds[i + 3][tid]), h3, a0);
            a1 = dot2_(bcu_(wlds[i + 32][tid]), h0, a1);
            a1 = dot2_(bcu_(wlds[i + 33][tid]), h1, a1);
            a1 = dot2_(bcu_(wlds[i + 34][tid]), h2, a1);
            a1 = dot2_(bcu_(wlds[i + 35][tid]), h3, a1);
        }
        zfin[c0] = a0 + xv0;
        zfin[c1] = a1 + xv1;
        __syncthreads();   // dots done (hl reads finished), zfin visible

        // ---- gates for h-col j = tid (tid < 256) ----
        if (tid < 256) {
            float zi = zfin[tid], zj = zfin[256 + tid];
            float zf = zfin[512 + tid], zo = zfin[768 + tid];
            float cn = sigmoidf_(zf + 1.0f) * cst + sigmoidf_(zi) * tanhf(zj);
            float hn = sigmoidf_(zo) * tanhf(cn);
            bool  msk = (tt < len);
            float ho  = msk ? hn : 0.f;
            float hk2 = msk ? hn : hprev;
            if (msk) cst = cn;
            hprev = hk2;
            lout[((size_t)(b * T_ + tt)) * (2 * H_) + dir * H_ + tid] = ho;
            hl[tid] = (_Float16)hk2;
        }
        __syncthreads();   // new h visible for next step
    }
}

// ---------------------------------------------------------------------------
// K4: einsum partials. Grid (8 m-groups, 32 b). lout[b] staged in LDS once;
// ent streamed (the mandatory 268 MB of HBM).
// ---------------------------------------------------------------------------
__global__ void __launch_bounds__(512)
k_einsum(const float* __restrict__ ent, const float* __restrict__ lout,
         float* __restrict__ partials) {
    const int mg = blockIdx.x;   // 0..7
    const int b  = blockIdx.y;   // 0..31
    const int d  = threadIdx.x;  // 0..511

    __shared__ float louts[T_][512];
    for (int t = 0; t < T_; ++t) louts[t][d] = lout[((size_t)(b * T_ + t)) * 512 + d];
    __syncthreads();

    for (int mi = 0; mi < 8; ++mi) {
        int m = mg * 8 + mi;
        const float* ep = ent + ((size_t)(m * B_ + b) * T_) * 512 + d;
        float acc = 0.f;
        #pragma unroll 4
        for (int t = 0; t < T_; ++t) acc += ep[(size_t)t * 512] * louts[t][d];
        partials[((size_t)m * B_ + b) * 512 + d] = acc;
    }
}

// ---------------------------------------------------------------------------
// K5: reduce partials over b -> output_f, then l1 = relu(of @ W1 + b1)
// ---------------------------------------------------------------------------
__global__ void k_l1(const float* __restrict__ partials, const float* __restrict__ W1,
                     const float* __restrict__ b1, float* __restrict__ l1) {
    const int m = blockIdx.x;
    const int j = threadIdx.x;  // 0..255
    __shared__ float of[512];
    for (int d = j; d < 512; d += 256) {
        float s = 0.f;
        #pragma unroll
        for (int cc = 0; cc < 32; ++cc) s += partials[((size_t)m * B_ + cc) * 512 + d];
        of[d] = s * (1.0f / T_);
    }
    __syncthreads();
    float z = b1[j];
    for (int k = 0; k < 512; ++k) z += of[k] * W1[(size_t)k * H_ + j];
    l1[(size_t)m * H_ + j] = fmaxf(z, 0.f);
}

// ---------------------------------------------------------------------------
// K6: head + loss
// ---------------------------------------------------------------------------
__global__ void k_head(const float* __restrict__ l1, const float* __restrict__ W2,
                       const float* __restrict__ b2, const int* __restrict__ labels,
                       float* __restrict__ out) {
    const int tid = threadIdx.x;  // 320 threads
    __shared__ float red[320];
    float term = 0.f;
    if (tid < 320) {
        int m = tid / 5, cc = tid % 5;
        float z = b2[cc];
        for (int k = 0; k < H_; ++k) z += l1[(size_t)m * H_ + k] * W2[(size_t)k * C_ + cc];
        float p = 1.f / (1.f + expf(-z));
        out[tid] = p;
        term = -(float)labels[tid] * logf(p);
    }
    red[tid] = term;
    __syncthreads();
    if (tid == 0) {
        float s = 0.f;
        for (int i = 0; i < 320; ++i) s += red[i];
        out[320] = s / (float)C_;
    }
}

// ---------------------------------------------------------------------------
extern "C" void kernel_launch(void* const* d_in, const int* in_sizes, int n_in,
                              void* d_out, int out_size, void* d_ws, size_t ws_size,
                              hipStream_t stream) {
    const float* x      = (const float*)d_in[0];
    const float* ent    = (const float*)d_in[1];
    const int*   labels = (const int*)d_in[2];
    const float* Wfw    = (const float*)d_in[3];
    const float* bfw    = (const float*)d_in[4];
    const float* Wbw    = (const float*)d_in[5];
    const float* bbw    = (const float*)d_in[6];
    const float* W1     = (const float*)d_in[7];
    const float* b1     = (const float*)d_in[8];
    const float* W2     = (const float*)d_in[9];
    const float* b2     = (const float*)d_in[10];
    float* out = (float*)d_out;

    float* ws     = (float*)d_ws;
    float* xw     = ws;                          // 4,194,304 floats
    float* lout   = xw + 4194304;                // 1,048,576 floats
    float* l1     = lout + 1048576;              // 16,384 floats
    int*   length = (int*)(l1 + 16384);          // 32 ints
    float* partials = xw;                        // alias: xw dead after k_lstm

    k_length<<<32, 64, 0, stream>>>(x, length);
    k_xw<<<dim3(16, 16), 256, 0, stream>>>(x, Wfw, bfw, Wbw, bbw, xw);
    k_lstm<<<64, 512, 0, stream>>>(Wfw, Wbw, xw, length, lout);
    k_einsum<<<dim3(8, 32), 512, 0, stream>>>(ent, lout, partials);
    k_l1<<<64, 256, 0, stream>>>(partials, W1, b1, l1);
    k_head<<<1, 320, 0, stream>>>(l1, W2, b2, labels, out);
}

// Round 7
// 272.642 us; speedup vs baseline: 1.6923x; 1.6923x over previous
//
#include <hip/hip_runtime.h>
#include <math.h>

#define B_   32
#define T_   64
#define D_   300
#define H_   256
#define G4H  1024   // 4*H
#define M_   64
#define C_   5

typedef _Float16 h2v __attribute__((ext_vector_type(2)));
typedef _Float16 h8  __attribute__((ext_vector_type(8)));
typedef float    f4  __attribute__((ext_vector_type(4)));

__device__ __forceinline__ float sigmoidf_(float x) { return 1.0f / (1.0f + expf(-x)); }

__device__ __forceinline__ float dot2_(h2v a, h2v b, float c) {
#if __has_builtin(__builtin_amdgcn_fdot2)
    return __builtin_amdgcn_fdot2(a, b, c, false);
#else
    return c + (float)a[0] * (float)b[0] + (float)a[1] * (float)b[1];
#endif
}

// ---------------------------------------------------------------------------
// K1: length[b]. Coalesced: 16 lanes per t read 64B-contiguous segments.
// 32 blocks (one per b) x 1024 threads (64 t x 16 lanes).
// ---------------------------------------------------------------------------
__global__ void __launch_bounds__(1024)
k_length(const float* __restrict__ x, int* __restrict__ length) {
    const int b   = blockIdx.x;
    const int tid = threadIdx.x;
    const int t   = tid >> 4;        // 0..63
    const int j   = tid & 15;        // lane within 16-group

    __shared__ int cnt;
    if (tid == 0) cnt = 0;
    __syncthreads();

    const float* row = x + (size_t)(b * T_ + t) * D_;
    float mv = 0.f;
    #pragma unroll
    for (int i = 0; i < 19; ++i) {
        int d = j + 16 * i;
        if (d < D_) mv = fmaxf(mv, fabsf(row[d]));
    }
    // reduce within the 16-lane group (stays inside one 64-lane wave)
    #pragma unroll
    for (int off = 8; off >= 1; off >>= 1) mv = fmaxf(mv, __shfl_xor(mv, off));
    if (j == 0 && mv > 0.f) atomicAdd(&cnt, 1);
    __syncthreads();
    if (tid == 0) length[b] = cnt;
}

// ---------------------------------------------------------------------------
// K2: xw = x-part of gate pre-activations (+ bias). f16 MFMA GEMM.
// ---------------------------------------------------------------------------
__global__ void __launch_bounds__(256)
k_xw(const float* __restrict__ x,
     const float* __restrict__ Wfw, const float* __restrict__ bfw,
     const float* __restrict__ Wbw, const float* __restrict__ bbw,
     float* __restrict__ xw) {
    const int nt  = blockIdx.x;       // 0..15 col tile
    const int mt  = blockIdx.y;       // 0..15 row tile
    const int tid = threadIdx.x;      // 256
    const int w   = tid >> 6;         // wave 0..3
    const int l   = tid & 63;
    const int n0  = nt * 128, m0 = mt * 128;
    const int dir = n0 >> 10;               // 1024%128==0: tiles don't straddle
    const float* W    = dir ? Wbw : Wfw;
    const float* bias = dir ? bbw : bfw;
    const int ncol0 = n0 & 1023;

    __shared__ __align__(16) _Float16 As[128][40];  // 32 k + 8 pad
    __shared__ __align__(16) _Float16 Bs[128][40];  // [col][k]

    f4 acc[4][4];
    #pragma unroll
    for (int i = 0; i < 4; ++i)
        #pragma unroll
        for (int j = 0; j < 4; ++j) acc[i][j] = (f4){0.f, 0.f, 0.f, 0.f};

    const int wr = (w >> 1) * 64;   // wave row quadrant
    const int wc = (w & 1) * 64;    // wave col quadrant

    for (int k0 = 0; k0 < 320; k0 += 32) {
        #pragma unroll
        for (int r = 0; r < 16; ++r) {
            int row = r * 8 + (tid >> 5);
            int kk  = tid & 31;
            int k   = k0 + kk;
            As[row][kk] = (k < D_) ? (_Float16)x[(size_t)(m0 + row) * D_ + k]
                                   : (_Float16)0.f;
        }
        #pragma unroll
        for (int r = 0; r < 16; ++r) {
            int col = (tid & 31) + (r & 3) * 32;
            int kk  = (tid >> 5) + (r >> 2) * 8;
            int k   = k0 + kk;
            Bs[col][kk] = (k < D_) ? (_Float16)W[(size_t)k * G4H + ncol0 + col]
                                   : (_Float16)0.f;
        }
        __syncthreads();

        h8 afr[4], bfr[4];
        #pragma unroll
        for (int fr = 0; fr < 4; ++fr)
            afr[fr] = *(const h8*)&As[wr + fr * 16 + (l & 15)][(l >> 4) * 8];
        #pragma unroll
        for (int fc = 0; fc < 4; ++fc)
            bfr[fc] = *(const h8*)&Bs[wc + fc * 16 + (l & 15)][(l >> 4) * 8];
        #pragma unroll
        for (int fr = 0; fr < 4; ++fr)
            #pragma unroll
            for (int fc = 0; fc < 4; ++fc)
                acc[fr][fc] = __builtin_amdgcn_mfma_f32_16x16x32_f16(
                    afr[fr], bfr[fc], acc[fr][fc], 0, 0, 0);
        __syncthreads();
    }

    #pragma unroll
    for (int fc = 0; fc < 4; ++fc) {
        int col = ncol0 + wc + fc * 16 + (l & 15);
        float bv = bias[col];
        #pragma unroll
        for (int fr = 0; fr < 4; ++fr) {
            #pragma unroll
            for (int e = 0; e < 4; ++e) {
                int row = m0 + wr + fr * 16 + (l >> 4) * 4 + e;
                xw[(size_t)dir * 2048 * G4H + (size_t)row * G4H + col] =
                    acc[fr][fc][e] + bv;
            }
        }
    }
}

// ---------------------------------------------------------------------------
// K3: LSTM recurrence (round-5 proven version). 256 blocks = 64 groups
// (dir,b) x 4 column-slices. W_h column-half in REGISTERS as f16 pairs
// (64 h2v per thread). Dot via v_dot2_f32_f16 + one shfl_xor(32).
// Cross-block h exchange: tagged-data protocol (fp32 LSB = ring-cycle
// parity, relaxed agent atomics, 4-slot ring).
// ---------------------------------------------------------------------------
__global__ void __launch_bounds__(512)
k_lstm(const float* __restrict__ Wfw, const float* __restrict__ Wbw,
       const float* __restrict__ xw, const int* __restrict__ length,
       float* __restrict__ lout, unsigned* __restrict__ exbuf) {
    const int bid = blockIdx.x;
    const int js  = bid >> 6;        // 0..3 column slice
    const int g   = bid & 63;        // group id
    const int dir = g >> 5;
    const int b   = g & 31;
    const int tid = threadIdx.x;     // 0..511
    const int w   = tid >> 6;        // wave 0..7
    const int l   = tid & 63;
    const int c     = w * 32 + (l & 31);   // gate-col 0..255 (gate = c>>6, jj = c&63)
    const int khalf = l >> 5;              // 0: k 0..127, 1: k 128..255
    const int colg  = (c >> 6) * 256 + js * 64 + (c & 63);

    __shared__ __align__(8) _Float16 hl_h[256];
    __shared__ float zfin[256];

    const float* Wg = dir ? Wbw : Wfw;

    // ---- stage this thread's W_h column-half into registers (f16 pairs) ----
    h2v wreg[64];
    #pragma unroll
    for (int p = 0; p < 64; ++p) {
        int k = khalf * 128 + 2 * p;
        float w0 = Wg[(size_t)(D_ + k) * G4H + colg];
        float w1 = Wg[(size_t)(D_ + k + 1) * G4H + colg];
        h2v t; t[0] = (_Float16)w0; t[1] = (_Float16)w1;
        wreg[p] = t;
    }

    if (tid < 256) hl_h[tid] = (_Float16)0.f;
    const int len = length[b];
    const size_t xrow = (size_t)(dir * B_ + b) * T_;
    __syncthreads();

    float cst = 0.f, hprev = 0.f;

    for (int s = 0; s < T_; ++s) {
        const int tt = dir ? (T_ - 1 - s) : s;
        const unsigned tag = ((unsigned)(s >> 2) & 1u) ^ 1u;   // ring-cycle parity
        const size_t slotBase = ((size_t)g * 4 + (s & 3)) * 256;

        // x-part (issued early; consumed at zfin write)
        float xv = 0.f;
        if (l < 32) xv = xw[(xrow + tt) * G4H + colg];

        // ---- dot: this col, this k-half: 32 broadcast b64 reads + 64 fdot2 ----
        float acc = 0.f;
        const uint2* hp = (const uint2*)&hl_h[khalf * 128];
        #pragma unroll
        for (int j = 0; j < 32; ++j) {
            uint2 hv = hp[j];
            acc = dot2_(wreg[2 * j],     __builtin_bit_cast(h2v, hv.x), acc);
            acc = dot2_(wreg[2 * j + 1], __builtin_bit_cast(h2v, hv.y), acc);
        }
        acc += __shfl_xor(acc, 32);          // combine the two k-halves
        if (l < 32) zfin[c] = acc + xv;
        __syncthreads();

        // ---- gates for this block's 64 h-columns; publish tagged h slice ----
        if (tid < 64) {
            float zi = zfin[tid], zj = zfin[64 + tid], zf = zfin[128 + tid], zo = zfin[192 + tid];
            float cn = sigmoidf_(zf + 1.0f) * cst + sigmoidf_(zi) * tanhf(zj);
            float hn = sigmoidf_(zo) * tanhf(cn);
            bool  msk = (tt < len);
            float ho  = msk ? hn : 0.f;
            float hk2 = msk ? hn : hprev;
            if (msk) cst = cn;
            hprev = hk2;
            int jglob = js * 64 + tid;
            lout[((size_t)(b * T_ + tt)) * (2 * H_) + dir * H_ + jglob] = ho;
            hl_h[jglob] = (_Float16)hk2;     // own slice straight into LDS
            unsigned bits = (__float_as_uint(hk2) & ~1u) | tag;
            __hip_atomic_store(&exbuf[slotBase + jglob], bits,
                               __ATOMIC_RELAXED, __HIP_MEMORY_SCOPE_AGENT);
        }

        // ---- poll peers' tagged words (single L3 trip, relaxed) ----
        if (tid < 256 && (tid >> 6) != js) {
            unsigned v; unsigned it = 0;
            for (;;) {
                v = __hip_atomic_load(&exbuf[slotBase + tid],
                                      __ATOMIC_RELAXED, __HIP_MEMORY_SCOPE_AGENT);
                if ((v & 1u) == tag) break;
                __builtin_amdgcn_s_sleep(1);
                if (++it > (1u << 20)) break;   // safety valve: wrong > wedged
            }
            hl_h[tid] = (_Float16)__uint_as_float(v);
        }
        __syncthreads();
    }
}

// ---------------------------------------------------------------------------
// K4: einsum partials. Grid (8 m-groups, 32 b). lout[b] staged in LDS once;
// ent streamed (the mandatory 268 MB of HBM). Unroll 8 for load ILP.
// ---------------------------------------------------------------------------
__global__ void __launch_bounds__(512)
k_einsum(const float* __restrict__ ent, const float* __restrict__ lout,
         float* __restrict__ partials) {
    const int mg = blockIdx.x;   // 0..7
    const int b  = blockIdx.y;   // 0..31
    const int d  = threadIdx.x;  // 0..511

    __shared__ float louts[T_][512];
    for (int t = 0; t < T_; ++t) louts[t][d] = lout[((size_t)(b * T_ + t)) * 512 + d];
    __syncthreads();

    for (int mi = 0; mi < 8; ++mi) {
        int m = mg * 8 + mi;
        const float* ep = ent + ((size_t)(m * B_ + b) * T_) * 512 + d;
        float acc = 0.f;
        #pragma unroll 8
        for (int t = 0; t < T_; ++t) acc += ep[(size_t)t * 512] * louts[t][d];
        partials[((size_t)m * B_ + b) * 512 + d] = acc;
    }
}

// ---------------------------------------------------------------------------
// K5: reduce partials over b -> output_f, then l1 = relu(of @ W1 + b1)
// ---------------------------------------------------------------------------
__global__ void k_l1(const float* __restrict__ partials, const float* __restrict__ W1,
                     const float* __restrict__ b1, float* __restrict__ l1) {
    const int m = blockIdx.x;
    const int j = threadIdx.x;  // 0..255
    __shared__ float of[512];
    for (int d = j; d < 512; d += 256) {
        float s = 0.f;
        #pragma unroll
        for (int cc = 0; cc < 32; ++cc) s += partials[((size_t)m * B_ + cc) * 512 + d];
        of[d] = s * (1.0f / T_);
    }
    __syncthreads();
    float z = b1[j];
    for (int k = 0; k < 512; ++k) z += of[k] * W1[(size_t)k * H_ + j];
    l1[(size_t)m * H_ + j] = fmaxf(z, 0.f);
}

// ---------------------------------------------------------------------------
// K6: head + loss
// ---------------------------------------------------------------------------
__global__ void k_head(const float* __restrict__ l1, const float* __restrict__ W2,
                       const float* __restrict__ b2, const int* __restrict__ labels,
                       float* __restrict__ out) {
    const int tid = threadIdx.x;  // 320 threads
    __shared__ float red[320];
    float term = 0.f;
    if (tid < 320) {
        int m = tid / 5, cc = tid % 5;
        float z = b2[cc];
        for (int k = 0; k < H_; ++k) z += l1[(size_t)m * H_ + k] * W2[(size_t)k * C_ + cc];
        float p = 1.f / (1.f + expf(-z));
        out[tid] = p;
        term = -(float)labels[tid] * logf(p);
    }
    red[tid] = term;
    __syncthreads();
    if (tid == 0) {
        float s = 0.f;
        for (int i = 0; i < 320; ++i) s += red[i];
        out[320] = s / (float)C_;
    }
}

// ---------------------------------------------------------------------------
extern "C" void kernel_launch(void* const* d_in, const int* in_sizes, int n_in,
                              void* d_out, int out_size, void* d_ws, size_t ws_size,
                              hipStream_t stream) {
    const float* x      = (const float*)d_in[0];
    const float* ent    = (const float*)d_in[1];
    const int*   labels = (const int*)d_in[2];
    const float* Wfw    = (const float*)d_in[3];
    const float* bfw    = (const float*)d_in[4];
    const float* Wbw    = (const float*)d_in[5];
    const float* bbw    = (const float*)d_in[6];
    const float* W1     = (const float*)d_in[7];
    const float* b1     = (const float*)d_in[8];
    const float* W2     = (const float*)d_in[9];
    const float* b2     = (const float*)d_in[10];
    float* out = (float*)d_out;

    float*    ws     = (float*)d_ws;
    float*    xw     = ws;                          // 4,194,304 floats
    float*    lout   = xw + 4194304;                // 1,048,576 floats
    unsigned* exbuf  = (unsigned*)(lout + 1048576); // 65,536 u32 (64 groups * 4 slots * 256)
    float*    l1     = (float*)(exbuf + 65536);     // 16,384 floats
    int*      length = (int*)(l1 + 16384);          // 32 ints
    float*    partials = xw;                        // alias: xw dead after k_lstm

    k_length<<<32, 1024, 0, stream>>>(x, length);
    k_xw<<<dim3(16, 16), 256, 0, stream>>>(x, Wfw, bfw, Wbw, bbw, xw);
    k_lstm<<<256, 512, 0, stream>>>(Wfw, Wbw, xw, length, lout, exbuf);
    k_einsum<<<dim3(8, 32), 512, 0, stream>>>(ent, lout, partials);
    k_l1<<<64, 256, 0, stream>>>(partials, W1, b1, l1);
    k_head<<<1, 320, 0, stream>>>(l1, W2, b2, labels, out);
}

// Round 8
// 202.139 us; speedup vs baseline: 2.2826x; 1.3488x over previous
//
#include <hip/hip_runtime.h>
#include <math.h>

#define B_   32
#define T_   64
#define D_   300
#define H_   256
#define G4H  1024   // 4*H
#define M_   64
#define C_   5

typedef _Float16 h2v __attribute__((ext_vector_type(2)));
typedef _Float16 h8  __attribute__((ext_vector_type(8)));
typedef float    f4  __attribute__((ext_vector_type(4)));

__device__ __forceinline__ float sigmoidf_(float x) { return 1.0f / (1.0f + expf(-x)); }

__device__ __forceinline__ float dot2_(h2v a, h2v b, float c) {
#if __has_builtin(__builtin_amdgcn_fdot2)
    return __builtin_amdgcn_fdot2(a, b, c, false);
#else
    return c + (float)a[0] * (float)b[0] + (float)a[1] * (float)b[1];
#endif
}

// ---------------------------------------------------------------------------
// K1: length[b]. Coalesced: 16 lanes per t read 64B-contiguous segments.
// ---------------------------------------------------------------------------
__global__ void __launch_bounds__(1024)
k_length(const float* __restrict__ x, int* __restrict__ length) {
    const int b   = blockIdx.x;
    const int tid = threadIdx.x;
    const int t   = tid >> 4;        // 0..63
    const int j   = tid & 15;        // lane within 16-group

    __shared__ int cnt;
    if (tid == 0) cnt = 0;
    __syncthreads();

    const float* row = x + (size_t)(b * T_ + t) * D_;
    float mv = 0.f;
    #pragma unroll
    for (int i = 0; i < 19; ++i) {
        int d = j + 16 * i;
        if (d < D_) mv = fmaxf(mv, fabsf(row[d]));
    }
    #pragma unroll
    for (int off = 8; off >= 1; off >>= 1) mv = fmaxf(mv, __shfl_xor(mv, off));
    if (j == 0 && mv > 0.f) atomicAdd(&cnt, 1);
    __syncthreads();
    if (tid == 0) length[b] = cnt;
}

// ---------------------------------------------------------------------------
// K2: xw = x-part of gate pre-activations (+ bias). f16 MFMA GEMM.
// Staging vectorized: float4 global loads (4x fewer VMEM instructions).
// ---------------------------------------------------------------------------
__global__ void __launch_bounds__(256)
k_xw(const float* __restrict__ x,
     const float* __restrict__ Wfw, const float* __restrict__ bfw,
     const float* __restrict__ Wbw, const float* __restrict__ bbw,
     float* __restrict__ xw) {
    const int nt  = blockIdx.x;       // 0..15 col tile
    const int mt  = blockIdx.y;       // 0..15 row tile
    const int tid = threadIdx.x;      // 256
    const int w   = tid >> 6;         // wave 0..3
    const int l   = tid & 63;
    const int n0  = nt * 128, m0 = mt * 128;
    const int dir = n0 >> 10;               // 1024%128==0: tiles don't straddle
    const float* W    = dir ? Wbw : Wfw;
    const float* bias = dir ? bbw : bfw;
    const int ncol0 = n0 & 1023;

    __shared__ __align__(16) _Float16 As[128][40];  // 32 k + 8 pad
    __shared__ __align__(16) _Float16 Bs[128][40];  // [col][k]

    f4 acc[4][4];
    #pragma unroll
    for (int i = 0; i < 4; ++i)
        #pragma unroll
        for (int j = 0; j < 4; ++j) acc[i][j] = (f4){0.f, 0.f, 0.f, 0.f};

    const int wr = (w >> 1) * 64;   // wave row quadrant
    const int wc = (w & 1) * 64;    // wave col quadrant

    for (int k0 = 0; k0 < 320; k0 += 32) {
        // A: 128 rows x 32 k, float4 along k (D_=300 is 4-aligned: chunk all-in or all-out)
        #pragma unroll
        for (int p = 0; p < 4; ++p) {
            int row = (tid >> 3) + p * 32;
            int kq  = tid & 7;
            int k   = k0 + kq * 4;
            f4 v = (k < D_) ? *(const f4*)&x[(size_t)(m0 + row) * D_ + k]
                            : (f4){0.f, 0.f, 0.f, 0.f};
            _Float16* dst = &As[row][kq * 4];
            dst[0] = (_Float16)v[0]; dst[1] = (_Float16)v[1];
            dst[2] = (_Float16)v[2]; dst[3] = (_Float16)v[3];
        }
        // B: 32 k x 128 cols, float4 along col
        #pragma unroll
        for (int p = 0; p < 4; ++p) {
            int kk   = (tid >> 5) + p * 8;
            int colq = tid & 31;
            int k    = k0 + kk;
            f4 v = (k < D_) ? *(const f4*)&W[(size_t)k * G4H + ncol0 + colq * 4]
                            : (f4){0.f, 0.f, 0.f, 0.f};
            #pragma unroll
            for (int i = 0; i < 4; ++i) Bs[colq * 4 + i][kk] = (_Float16)v[i];
        }
        __syncthreads();

        h8 afr[4], bfr[4];
        #pragma unroll
        for (int fr = 0; fr < 4; ++fr)
            afr[fr] = *(const h8*)&As[wr + fr * 16 + (l & 15)][(l >> 4) * 8];
        #pragma unroll
        for (int fc = 0; fc < 4; ++fc)
            bfr[fc] = *(const h8*)&Bs[wc + fc * 16 + (l & 15)][(l >> 4) * 8];
        #pragma unroll
        for (int fr = 0; fr < 4; ++fr)
            #pragma unroll
            for (int fc = 0; fc < 4; ++fc)
                acc[fr][fc] = __builtin_amdgcn_mfma_f32_16x16x32_f16(
                    afr[fr], bfr[fc], acc[fr][fc], 0, 0, 0);
        __syncthreads();
    }

    #pragma unroll
    for (int fc = 0; fc < 4; ++fc) {
        int col = ncol0 + wc + fc * 16 + (l & 15);
        float bv = bias[col];
        #pragma unroll
        for (int fr = 0; fr < 4; ++fr) {
            #pragma unroll
            for (int e = 0; e < 4; ++e) {
                int row = m0 + wr + fr * 16 + (l >> 4) * 4 + e;
                xw[(size_t)dir * 2048 * G4H + (size_t)row * G4H + col] =
                    acc[fr][fc][e] + bv;
            }
        }
    }
}

// ---------------------------------------------------------------------------
// K3: LSTM recurrence + FUSED einsum. 256 blocks = 64 groups (dir,b) x 4
// column-slices. W_h column-half in registers (64 h2v/thread, fdot2 dot,
// shfl_xor(32) combine). Cross-block h exchange: tagged-data protocol
// (fp32 LSB = ring-cycle parity, relaxed agent atomics, 4-slot ring).
// Einsum fusion: per step, every thread prefetches its 8 ent floats
// (m8 = tid>>3, d = js*64 + (tid&7)*8 ..+7) at loop top and MACs them
// against this block's masked h-slice (ho_l LDS) at loop bottom —
// the 268 MB ent stream rides in the latency shadow of the L3 exchange.
// lout is never materialized; partials written once at the end.
// ---------------------------------------------------------------------------
__global__ void __launch_bounds__(512)
k_lstm(const float* __restrict__ Wfw, const float* __restrict__ Wbw,
       const float* __restrict__ xw, const int* __restrict__ length,
       const float* __restrict__ ent, float* __restrict__ partials,
       unsigned* __restrict__ exbuf) {
    const int bid = blockIdx.x;
    const int js  = bid >> 6;        // 0..3 column slice
    const int g   = bid & 63;        // group id
    const int dir = g >> 5;
    const int b   = g & 31;
    const int tid = threadIdx.x;     // 0..511
    const int w   = tid >> 6;        // wave 0..7
    const int l   = tid & 63;
    const int c     = w * 32 + (l & 31);   // gate-col 0..255 (gate = c>>6, jj = c&63)
    const int khalf = l >> 5;              // 0: k 0..127, 1: k 128..255
    const int colg  = (c >> 6) * 256 + js * 64 + (c & 63);
    const int m8  = tid >> 3;        // einsum m 0..63
    const int oct = tid & 7;         // einsum d-octet

    __shared__ __align__(8) _Float16 hl_h[256];
    __shared__ float zfin[256];
    __shared__ float ho_l[64];

    const float* Wg = dir ? Wbw : Wfw;

    // ---- stage this thread's W_h column-half into registers (f16 pairs) ----
    h2v wreg[64];
    #pragma unroll
    for (int p = 0; p < 64; ++p) {
        int k = khalf * 128 + 2 * p;
        float w0 = Wg[(size_t)(D_ + k) * G4H + colg];
        float w1 = Wg[(size_t)(D_ + k + 1) * G4H + colg];
        h2v t; t[0] = (_Float16)w0; t[1] = (_Float16)w1;
        wreg[p] = t;
    }

    if (tid < 256) hl_h[tid] = (_Float16)0.f;
    const int len = length[b];
    const size_t xrow = (size_t)(dir * B_ + b) * T_;
    // einsum base for this thread: ent[m8, b, t, dir*256 + js*64 + oct*8]
    const float* entp = ent + (((size_t)m8 * B_ + b) * T_) * 512
                            + dir * 256 + js * 64 + oct * 8;
    f4 accA = (f4){0.f, 0.f, 0.f, 0.f};
    f4 accB = (f4){0.f, 0.f, 0.f, 0.f};
    __syncthreads();

    float cst = 0.f, hprev = 0.f;

    for (int s = 0; s < T_; ++s) {
        const int tt = dir ? (T_ - 1 - s) : s;
        const unsigned tag = ((unsigned)(s >> 2) & 1u) ^ 1u;   // ring-cycle parity
        const size_t slotBase = ((size_t)g * 4 + (s & 3)) * 256;

        // prefetch einsum operands for this step (independent of recurrence)
        f4 e0 = *(const f4*)(entp + (size_t)tt * 512);
        f4 e1 = *(const f4*)(entp + (size_t)tt * 512 + 4);

        // x-part (issued early; consumed at zfin write)
        float xv = 0.f;
        if (l < 32) xv = xw[(xrow + tt) * G4H + colg];

        // ---- dot: this col, this k-half: 32 broadcast b64 reads + 64 fdot2 ----
        float acc = 0.f;
        const uint2* hp = (const uint2*)&hl_h[khalf * 128];
        #pragma unroll
        for (int j = 0; j < 32; ++j) {
            uint2 hv = hp[j];
            acc = dot2_(wreg[2 * j],     __builtin_bit_cast(h2v, hv.x), acc);
            acc = dot2_(wreg[2 * j + 1], __builtin_bit_cast(h2v, hv.y), acc);
        }
        acc += __shfl_xor(acc, 32);          // combine the two k-halves
        if (l < 32) zfin[c] = acc + xv;
        __syncthreads();

        // ---- gates for this block's 64 h-columns; publish tagged h slice ----
        if (tid < 64) {
            float zi = zfin[tid], zj = zfin[64 + tid], zf = zfin[128 + tid], zo = zfin[192 + tid];
            float cn = sigmoidf_(zf + 1.0f) * cst + sigmoidf_(zi) * tanhf(zj);
            float hn = sigmoidf_(zo) * tanhf(cn);
            bool  msk = (tt < len);
            float ho  = msk ? hn : 0.f;
            float hk2 = msk ? hn : hprev;
            if (msk) cst = cn;
            hprev = hk2;
            int jglob = js * 64 + tid;
            ho_l[tid] = ho;                  // masked output for fused einsum
            hl_h[jglob] = (_Float16)hk2;     // own slice straight into LDS
            unsigned bits = (__float_as_uint(hk2) & ~1u) | tag;
            __hip_atomic_store(&exbuf[slotBase + jglob], bits,
                               __ATOMIC_RELAXED, __HIP_MEMORY_SCOPE_AGENT);
        }

        // ---- poll peers' tagged words (single L3 trip, relaxed) ----
        if (tid < 256 && (tid >> 6) != js) {
            unsigned v; unsigned it = 0;
            for (;;) {
                v = __hip_atomic_load(&exbuf[slotBase + tid],
                                      __ATOMIC_RELAXED, __HIP_MEMORY_SCOPE_AGENT);
                if ((v & 1u) == tag) break;
                __builtin_amdgcn_s_sleep(1);
                if (++it > (1u << 20)) break;   // safety valve: wrong > wedged
            }
            hl_h[tid] = (_Float16)__uint_as_float(v);
        }
        __syncthreads();

        // ---- fused einsum MAC (ho_l stable until next gates, which is
        //      barrier-separated; e0/e1 prefetched at loop top) ----
        #pragma unroll
        for (int i = 0; i < 4; ++i) {
            accA[i] += e0[i] * ho_l[oct * 8 + i];
            accB[i] += e1[i] * ho_l[oct * 8 + 4 + i];
        }
    }

    // ---- write partials: unique region per block: (m8, b, 64-d slice) ----
    float* pp = partials + ((size_t)m8 * B_ + b) * 512 + dir * 256 + js * 64 + oct * 8;
    *(f4*)pp = accA;
    *(f4*)(pp + 4) = accB;
}

// ---------------------------------------------------------------------------
// K5: reduce partials over b -> output_f, then l1 = relu(of @ W1 + b1)
// ---------------------------------------------------------------------------
__global__ void k_l1(const float* __restrict__ partials, const float* __restrict__ W1,
                     const float* __restrict__ b1, float* __restrict__ l1) {
    const int m = blockIdx.x;
    const int j = threadIdx.x;  // 0..255
    __shared__ float of[512];
    for (int d = j; d < 512; d += 256) {
        float s = 0.f;
        #pragma unroll
        for (int cc = 0; cc < 32; ++cc) s += partials[((size_t)m * B_ + cc) * 512 + d];
        of[d] = s * (1.0f / T_);
    }
    __syncthreads();
    float z = b1[j];
    for (int k = 0; k < 512; ++k) z += of[k] * W1[(size_t)k * H_ + j];
    l1[(size_t)m * H_ + j] = fmaxf(z, 0.f);
}

// ---------------------------------------------------------------------------
// K6: head + loss
// ---------------------------------------------------------------------------
__global__ void k_head(const float* __restrict__ l1, const float* __restrict__ W2,
                       const float* __restrict__ b2, const int* __restrict__ labels,
                       float* __restrict__ out) {
    const int tid = threadIdx.x;  // 320 threads
    __shared__ float red[320];
    float term = 0.f;
    if (tid < 320) {
        int m = tid / 5, cc = tid % 5;
        float z = b2[cc];
        for (int k = 0; k < H_; ++k) z += l1[(size_t)m * H_ + k] * W2[(size_t)k * C_ + cc];
        float p = 1.f / (1.f + expf(-z));
        out[tid] = p;
        term = -(float)labels[tid] * logf(p);
    }
    red[tid] = term;
    __syncthreads();
    if (tid == 0) {
        float s = 0.f;
        for (int i = 0; i < 320; ++i) s += red[i];
        out[320] = s / (float)C_;
    }
}

// ---------------------------------------------------------------------------
extern "C" void kernel_launch(void* const* d_in, const int* in_sizes, int n_in,
                              void* d_out, int out_size, void* d_ws, size_t ws_size,
                              hipStream_t stream) {
    const float* x      = (const float*)d_in[0];
    const float* ent    = (const float*)d_in[1];
    const int*   labels = (const int*)d_in[2];
    const float* Wfw    = (const float*)d_in[3];
    const float* bfw    = (const float*)d_in[4];
    const float* Wbw    = (const float*)d_in[5];
    const float* bbw    = (const float*)d_in[6];
    const float* W1     = (const float*)d_in[7];
    const float* b1     = (const float*)d_in[8];
    const float* W2     = (const float*)d_in[9];
    const float* b2     = (const float*)d_in[10];
    float* out = (float*)d_out;

    float*    ws       = (float*)d_ws;
    float*    xw       = ws;                            // 4,194,304 floats
    unsigned* exbuf    = (unsigned*)(xw + 4194304);     // 65,536 u32
    float*    l1       = (float*)(exbuf + 65536);       // 16,384 floats
    int*      length   = (int*)(l1 + 16384);            // 32 ints
    float*    partials = (float*)(length + 32);         // 1,048,576 floats

    k_length<<<32, 1024, 0, stream>>>(x, length);
    k_xw<<<dim3(16, 16), 256, 0, stream>>>(x, Wfw, bfw, Wbw, bbw, xw);
    k_lstm<<<256, 512, 0, stream>>>(Wfw, Wbw, xw, length, ent, partials, exbuf);
    k_l1<<<64, 256, 0, stream>>>(partials, W1, b1, l1);
    k_head<<<1, 320, 0, stream>>>(l1, W2, b2, labels, out);
}